// Round 14
// baseline (286.487 us; speedup 1.0000x reference)
//
#include <hip/hip_runtime.h>
#include <math.h>

#define TT 256
#define WARM 16
// ws float offsets (chain outputs + scan intermediates only)
#define OFF_K    5632   // 17 x 512 -> 14336
#define OFF_MC   14336  // 17 x 256 -> 18688
#define OFF_NB   18688  // 17 x 128 -> 20864
#define OFF_P0   20864  // Mseg0 (256) -> 21120
#define OFF_PP   21120  // Mc16^16 (256) -> 21376
#define OFF_WSEG 21376  // 16 x 256 x 16 -> 86912
#define NEED_WS_BYTES ((size_t)86912 * 4)

__device__ __forceinline__ float softplus(float v) {
    return fmaxf(v, 0.0f) + log1pf(expf(-fabsf(v)));
}

// Shuffle-based Gauss-Jordan, [X|I] -> [I|X^-1] (verified R5-R13).
__device__ __forceinline__ void gj16(float (&aug)[8], const int i, const int gq) {
#pragma unroll
    for (int j = 0; j < 16; ++j) {
        float prow[8];
#pragma unroll
        for (int k = 0; k < 8; ++k) prow[k] = __shfl(aug[k], j + 16 * gq);
        const float pjj = __shfl(aug[j & 7], j + 16 * (j >> 3));
        const float cij = __shfl(aug[j & 7], i + 16 * (j >> 3));
        const float pivinv = 1.0f / pjj;
        const float f = cij * pivinv;
#pragma unroll
        for (int k = 0; k < 8; ++k)
            aug[k] = (i == j) ? prow[k] * pivinv : aug[k] - f * prow[k];
    }
}

// ---------------------------------------------------------------------------
// Fused chain kernel (verified R13, unchanged): 17 blocks x 64 threads.
// QR, assembly, interleaved LSB-first double-and-apply, epilogue.
// ---------------------------------------------------------------------------
__global__ __launch_bounds__(64) void chain_k(
    const float* __restrict__ Mm, const float* __restrict__ Nm,
    const float* __restrict__ dvec, const float* __restrict__ Bm,
    const float* __restrict__ Cm, const float* __restrict__ nx,
    const float* __restrict__ na, const float* __restrict__ cov0,
    float* __restrict__ wsK, float* __restrict__ wsM, float* __restrict__ wsN)
{
    __shared__ float qm[16][17], qn[16][17], T0s[16][17];
    __shared__ float sC[32][17], sW[16][33], sAm[16][17], sBm[16][9];
    __shared__ float sE[16][17], sF[16][17], sH[16][17], sScr[16][17];
    __shared__ float sCA[32][17], sCB[32][9], sP[16][17], sK[16][33];
    __shared__ float spv[16], d2[16], sNai[32], sNxi[16];
    const int lane = threadIdx.x;
    const int t = blockIdx.x;            // 0..16
    const int n = t + 1;                 // steps to apply
    const int i = lane & 15, gq = lane >> 4, h = gq & 1;

    for (int e = lane; e < 256; e += 64) { qm[e >> 4][e & 15] = Mm[e]; qn[e >> 4][e & 15] = Nm[e]; }
    for (int e = lane; e < 512; e += 64) sC[e >> 4][e & 15] = Cm[e];
    for (int e = lane; e < 128; e += 64) sBm[e >> 3][e & 7] = Bm[e];
    if (lane < 16) {
        float s = softplus(dvec[lane]);
        spv[lane] = sqrtf(s);
        d2[lane] = 1.0f / sqrtf(1.0f + s);
        sNxi[lane] = 1.0f / (softplus(nx[lane]) + 1e-4f);
    }
    if (lane < 32) sNai[lane] = 1.0f / (softplus(na[lane]) + 1e-4f);
    __syncthreads();

    // register MGS QR (verified R12/R13)
    {
        const int j0 = lane & 15;
        const int mi = lane >> 4;
        float (*Qs)[17] = (mi == 1) ? qn : qm;
        float col[16];
#pragma unroll
        for (int r = 0; r < 16; ++r) col[r] = Qs[r][j0];
        const int base = lane & 48;
#pragma unroll 1
        for (int j = 0; j < 16; ++j) {
            float qj[16];
#pragma unroll
            for (int r = 0; r < 16; ++r) qj[r] = __shfl(col[r], base + j);
            float nrm = 0.f;
#pragma unroll
            for (int r = 0; r < 16; ++r) nrm += qj[r] * qj[r];
            const float scal = 1.0f / sqrtf(nrm);
#pragma unroll
            for (int r = 0; r < 16; ++r) qj[r] *= scal;
            if (j0 == j) {
#pragma unroll
                for (int r = 0; r < 16; ++r) col[r] = qj[r];
            } else if (j0 > j) {
                float pr = 0.f;
#pragma unroll
                for (int r = 0; r < 16; ++r) pr += qj[r] * col[r];
#pragma unroll
                for (int r = 0; r < 16; ++r) col[r] -= pr * qj[r];
            }
        }
        __syncthreads();
        if (mi < 2) {
#pragma unroll
            for (int r = 0; r < 16; ++r) Qs[r][j0] = col[r];
        }
    }
    __syncthreads();

    // assembly (verified R13)
    for (int e = lane; e < 256; e += 64) {
        int ii = e >> 4, j = e & 15;
        float s = 0.f;
        for (int q = 0; q < 16; ++q) s += qm[ii][q] * d2[q] * qn[j][q];
        T0s[ii][j] = spv[ii] * s;
    }
    __syncthreads();
    for (int e = lane; e < 256; e += 64) {
        int ii = e >> 4, j = e & 15;
        float s = 0.f;
        for (int q = 0; q < 16; ++q) s += qn[ii][q] * T0s[q][j];
        sAm[ii][j] = s;
    }
    for (int e = lane; e < 512; e += 64) {
        int q = e >> 5, r = e & 31;
        sW[q][r] = sC[r][q] * sNai[r];
    }
    __syncthreads();
    for (int e = lane; e < 256; e += 64) {
        int ii = e >> 4, j = e & 15;
        float g = 0.f;
        for (int r = 0; r < 32; ++r) g += sC[r][ii] * sW[j][r];
        sF[ii][j] = g + ((ii == j) ? sNxi[ii] : 0.f);
        sE[ii][j] = sNxi[ii] * sAm[ii][j];
        float hsum = 0.f;
        for (int q = 0; q < 16; ++q) hsum += sAm[q][ii] * sNxi[q] * sAm[q][j];
        sH[ii][j] = hsum;
    }
    for (int e = lane; e < 512; e += 64) {
        int r = e >> 4, j = e & 15;
        float s = 0.f;
        for (int q = 0; q < 16; ++q) s += sC[r][q] * sAm[q][j];
        sCA[r][j] = s;
    }
    for (int e = lane; e < 256; e += 64) {
        int r = e >> 3, j = e & 7;
        float s = 0.f;
        for (int q = 0; q < 16; ++q) s += sC[r][q] * sBm[q][j];
        sCB[r][j] = s;
    }
    __syncthreads();

    float Erow[16], ETrow[16], Fr[8], Hr[8];
#pragma unroll
    for (int q = 0; q < 16; ++q) { Erow[q] = sE[i][q]; ETrow[q] = sE[q][i]; }
#pragma unroll
    for (int k = 0; k < 8; ++k) { Fr[k] = sF[i][8 * h + k]; Hr[k] = sH[i][8 * h + k]; }

    float aug[8];
#pragma unroll
    for (int k = 0; k < 8; ++k)
        aug[k] = (gq < 2) ? cov0[i * 16 + 8 * gq + k]
                          : ((8 * (gq - 2) + k == i) ? 1.f : 0.f);
    gj16(aug, i, gq);
    float L_r[8];
#pragma unroll
    for (int k = 0; k < 8; ++k) L_r[k] = __shfl(aug[k], i + 16 * (2 + h));

#pragma unroll 1
    for (int m = 0; m < 5; ++m) {
        if ((n >> m) & 1) {
#pragma unroll
            for (int k = 0; k < 8; ++k)
                aug[k] = (gq < 2) ? (L_r[k] + Hr[k]) : ((8 * (gq - 2) + k == i) ? 1.f : 0.f);
            gj16(aug, i, gq);
            float T_r[8];
#pragma unroll
            for (int k = 0; k < 8; ++k) T_r[k] = 0.f;
#pragma unroll
            for (int q = 0; q < 16; ++q) {
                const float eq = Erow[q];
#pragma unroll
                for (int k = 0; k < 8; ++k) T_r[k] += eq * __shfl(aug[k], q + 16 * (2 + h));
            }
            float Trow[16];
#pragma unroll
            for (int q = 0; q < 16; ++q) Trow[q] = __shfl(T_r[q & 7], i + 16 * (q >> 3));
#pragma unroll
            for (int k = 0; k < 8; ++k) L_r[k] = Fr[k];
#pragma unroll
            for (int q = 0; q < 16; ++q) {
                const float tq = Trow[q];
#pragma unroll
                for (int k = 0; k < 8; ++k) L_r[k] -= tq * __shfl(Erow[q], 8 * h + k);
            }
        }
        if (m < 4) {
#pragma unroll
            for (int k = 0; k < 8; ++k)
                aug[k] = (gq < 2) ? (Fr[k] + Hr[k]) : ((8 * (gq - 2) + k == i) ? 1.f : 0.f);
            gj16(aug, i, gq);
            float Z_r[8];
#pragma unroll
            for (int k = 0; k < 8; ++k) Z_r[k] = __shfl(aug[k], i + 16 * (2 + h));
            float T_r[8], T2_r[8];
#pragma unroll
            for (int k = 0; k < 8; ++k) { T_r[k] = 0.f; T2_r[k] = 0.f; }
#pragma unroll
            for (int q = 0; q < 16; ++q) {
                const float eq = Erow[q], etq = ETrow[q];
#pragma unroll
                for (int k = 0; k < 8; ++k) {
                    const float z = __shfl(Z_r[k], q + 16 * h);
                    T_r[k] += eq * z;
                    T2_r[k] += etq * z;
                }
            }
            float Trow[16], T2row[16];
#pragma unroll
            for (int q = 0; q < 16; ++q) {
                Trow[q] = __shfl(T_r[q & 7], i + 16 * (q >> 3));
                T2row[q] = __shfl(T2_r[q & 7], i + 16 * (q >> 3));
            }
            float F2r[8], H2r[8], E2r[8];
#pragma unroll
            for (int k = 0; k < 8; ++k) { F2r[k] = Fr[k]; H2r[k] = Hr[k]; E2r[k] = 0.f; }
#pragma unroll
            for (int q = 0; q < 16; ++q) {
                const float tq = Trow[q], t2q = T2row[q];
#pragma unroll
                for (int k = 0; k < 8; ++k) {
                    const float ecol = __shfl(Erow[q], 8 * h + k);
                    const float etcol = __shfl(ETrow[q], 8 * h + k);
                    F2r[k] -= tq * ecol;
                    H2r[k] -= t2q * etcol;
                    E2r[k] += tq * etcol;
                }
            }
            __syncthreads();
            if (lane < 32) {
#pragma unroll
                for (int k = 0; k < 8; ++k) sScr[i][8 * h + k] = E2r[k];
            }
            __syncthreads();
#pragma unroll
            for (int q = 0; q < 16; ++q) { Erow[q] = sScr[i][q]; ETrow[q] = sScr[q][i]; }
#pragma unroll
            for (int k = 0; k < 8; ++k) { Fr[k] = F2r[k]; Hr[k] = H2r[k]; }
        }
    }

    // epilogue (verified)
#pragma unroll
    for (int k = 0; k < 8; ++k)
        aug[k] = (gq < 2) ? L_r[k] : ((8 * (gq - 2) + k == i) ? 1.f : 0.f);
    gj16(aug, i, gq);
    float P_r[8];
#pragma unroll
    for (int k = 0; k < 8; ++k) P_r[k] = __shfl(aug[k], i + 16 * (2 + h));
    if (lane < 32) {
#pragma unroll
        for (int k = 0; k < 8; ++k) sP[i][8 * h + k] = P_r[k];
    }
    __syncthreads();
#pragma unroll
    for (int m = 0; m < 8; ++m) {
        const int e = lane + 64 * m, ii = e >> 5, rr = e & 31;
        float s = 0.f;
#pragma unroll
        for (int q = 0; q < 16; ++q) s += sP[ii][q] * sW[q][rr];
        sK[ii][rr] = s;
        wsK[(size_t)t * 512 + e] = s;
    }
    __syncthreads();
#pragma unroll
    for (int m = 0; m < 4; ++m) {
        const int e = lane + 64 * m, ii = e >> 4, jj = e & 15;
        float s = sAm[ii][jj];
#pragma unroll
        for (int r = 0; r < 32; ++r) s -= sK[ii][r] * sCA[r][jj];
        wsM[(size_t)t * 256 + e] = s;
    }
#pragma unroll
    for (int m = 0; m < 2; ++m) {
        const int e = lane + 64 * m, ii = e >> 3, jj = e & 7;
        float s = sBm[ii][jj];
#pragma unroll
        for (int r = 0; r < 32; ++r) s -= sK[ii][r] * sCB[r][jj];
        wsN[(size_t)t * 128 + e] = s;
    }
}

// ---------------------------------------------------------------------------
// Phase A (R14): gv via direct broadcast-loads of a/u (bit-identical values
// to the verified shfl form: same elements, same order), Mc dedup for seg!=0.
// Blocks 0 and 256 also emit P0/PP (verified R10-R13 emitters).
// ---------------------------------------------------------------------------
__global__ __launch_bounds__(64) void phA_k(
    const float* __restrict__ u, const float* __restrict__ a,
    const float* __restrict__ wsK, const float* __restrict__ wsM,
    const float* __restrict__ wsN, float* __restrict__ wseg,
    float* __restrict__ wsp)
{
    const int lane = threadIdx.x;
    const int i = lane & 15, g = lane >> 4;
    const int seg = blockIdx.x >> 8;
    const int b = blockIdx.x & 255;

    float mcs[16][4];
    if (seg == 0) {
#pragma unroll
        for (int j = 0; j < 16; ++j) {
            const float4 v = *(const float4*)(wsM + (size_t)j * 256 + i * 16 + 4 * g);
            mcs[j][0] = v.x; mcs[j][1] = v.y; mcs[j][2] = v.z; mcs[j][3] = v.w;
        }
    } else {
        const float4 v = *(const float4*)(wsM + (size_t)16 * 256 + i * 16 + 4 * g);
        mcs[0][0] = v.x; mcs[0][1] = v.y; mcs[0][2] = v.z; mcs[0][3] = v.w;
    }
    float kc[8], nbc[8];
    if (seg != 0) {
        const float4 k0 = *(const float4*)(wsK + (size_t)16 * 512 + i * 32 + 8 * g);
        const float4 k1 = *(const float4*)(wsK + (size_t)16 * 512 + i * 32 + 8 * g + 4);
        const float4 n0 = *(const float4*)(wsN + (size_t)16 * 128 + i * 8);
        const float4 n1 = *(const float4*)(wsN + (size_t)16 * 128 + i * 8 + 4);
        kc[0]=k0.x; kc[1]=k0.y; kc[2]=k0.z; kc[3]=k0.w;
        kc[4]=k1.x; kc[5]=k1.y; kc[6]=k1.z; kc[7]=k1.w;
        nbc[0]=n0.x; nbc[1]=n0.y; nbc[2]=n0.z; nbc[3]=n0.w;
        nbc[4]=n1.x; nbc[5]=n1.y; nbc[6]=n1.z; nbc[7]=n1.w;
    }

    const float* ab = a + (size_t)b * (TT * 32);
    const float* ub = u + (size_t)b * (TT * 8);

    float w = 0.f;
#pragma unroll
    for (int j = 0; j < 16; ++j) {
        const int t = 16 * seg + j;
        float kr[8], nbr[8];
        if (seg == 0) {
            const float4 k0 = *(const float4*)(wsK + (size_t)j * 512 + i * 32 + 8 * g);
            const float4 k1 = *(const float4*)(wsK + (size_t)j * 512 + i * 32 + 8 * g + 4);
            const float4 n0 = *(const float4*)(wsN + (size_t)j * 128 + i * 8);
            const float4 n1 = *(const float4*)(wsN + (size_t)j * 128 + i * 8 + 4);
            kr[0]=k0.x; kr[1]=k0.y; kr[2]=k0.z; kr[3]=k0.w;
            kr[4]=k1.x; kr[5]=k1.y; kr[6]=k1.z; kr[7]=k1.w;
            nbr[0]=n0.x; nbr[1]=n0.y; nbr[2]=n0.z; nbr[3]=n0.w;
            nbr[4]=n1.x; nbr[5]=n1.y; nbr[6]=n1.z; nbr[7]=n1.w;
        } else {
#pragma unroll
            for (int k = 0; k < 8; ++k) { kr[k] = kc[k]; nbr[k] = nbc[k]; }
        }
        // direct broadcast loads (replace 16 shfl)
        const float4 av0 = *(const float4*)(ab + t * 32 + 8 * g);
        const float4 av1 = *(const float4*)(ab + t * 32 + 8 * g + 4);
        const float4 uv0 = *(const float4*)(ub + t * 8);
        const float4 uv1 = *(const float4*)(ub + t * 8 + 4);
        float gvp = kr[0]*av0.x + kr[1]*av0.y + kr[2]*av0.z + kr[3]*av0.w
                  + kr[4]*av1.x + kr[5]*av1.y + kr[6]*av1.z + kr[7]*av1.w;
        float nbs = nbr[0]*uv0.x + nbr[1]*uv0.y + nbr[2]*uv0.z + nbr[3]*uv0.w
                  + nbr[4]*uv1.x + nbr[5]*uv1.y + nbr[6]*uv1.z + nbr[7]*uv1.w;
        gvp += (g == 3) ? nbs : 0.f;
        gvp += __shfl_xor(gvp, 16);
        gvp += __shfl_xor(gvp, 32);
        const float* mr = (seg == 0) ? mcs[j] : mcs[0];
        float part = mr[0] * __shfl(w, 4*g+0) + mr[1] * __shfl(w, 4*g+1)
                   + mr[2] * __shfl(w, 4*g+2) + mr[3] * __shfl(w, 4*g+3);
        part += __shfl_xor(part, 16);
        part += __shfl_xor(part, 32);
        w = part + gvp;
    }
    if (lane < 16) wseg[(size_t)seg * 4096 + b * 16 + i] = w;

    if (blockIdx.x == 0) {          // P0 = Mc15 ... Mc0
        float pr[4];
#pragma unroll
        for (int k = 0; k < 4; ++k) pr[k] = (4 * g + k == i) ? 1.f : 0.f;
#pragma unroll
        for (int j = 0; j < 16; ++j) {
            float np[4] = {0.f, 0.f, 0.f, 0.f};
#pragma unroll
            for (int q = 0; q < 16; ++q) {
                const float mq = __shfl(mcs[j][q & 3], i + 16 * (q >> 2));
#pragma unroll
                for (int k = 0; k < 4; ++k) np[k] += mq * __shfl(pr[k], q + 16 * g);
            }
#pragma unroll
            for (int k = 0; k < 4; ++k) pr[k] = np[k];
        }
#pragma unroll
        for (int k = 0; k < 4; ++k) wsp[i * 16 + 4 * g + k] = pr[k];
    }
    if (blockIdx.x == 256) {        // PP = Mc16^16 (mcs[0] = Mc_16)
        float pr[4];
#pragma unroll
        for (int k = 0; k < 4; ++k) pr[k] = mcs[0][k];
#pragma unroll
        for (int r = 0; r < 4; ++r) {
            float np[4] = {0.f, 0.f, 0.f, 0.f};
#pragma unroll
            for (int q = 0; q < 16; ++q) {
                const float sq = __shfl(pr[q & 3], i + 16 * (q >> 2));
#pragma unroll
                for (int k = 0; k < 4; ++k) np[k] += sq * __shfl(pr[k], q + 16 * g);
            }
#pragma unroll
            for (int k = 0; k < 4; ++k) pr[k] = np[k];
        }
#pragma unroll
        for (int k = 0; k < 4; ++k) wsp[256 + i * 16 + 4 * g + k] = pr[k];
    }
}

// ---------------------------------------------------------------------------
// Phase BC (R14): phB fused into phC. Each (seg,b) block replays its own
// boundary recursion (bit-identical sequence to the verified phB), then
// regenerates interiors with direct-load gv and emits outputs.
// ---------------------------------------------------------------------------
__global__ __launch_bounds__(64) void phBC_k(
    const float* __restrict__ mean0, const float* __restrict__ u,
    const float* __restrict__ a, const float* __restrict__ wsK,
    const float* __restrict__ wsM, const float* __restrict__ wsN,
    const float* __restrict__ wsp, const float* __restrict__ wseg,
    float* __restrict__ out)
{
    const int lane = threadIdx.x;
    const int i = lane & 15, g = lane >> 4;
    const int seg = blockIdx.x >> 8;
    const int b = blockIdx.x & 255;

    // ---- boundary: mn = mn_{16*seg} via seg serial steps (verified phB) ----
    const float4 v0 = *(const float4*)(wsp + i * 16 + 4 * g);
    const float4 vp = *(const float4*)(wsp + 256 + i * 16 + 4 * g);
    const float m0s[4] = {v0.x, v0.y, v0.z, v0.w};
    const float mps[4] = {vp.x, vp.y, vp.z, vp.w};

    float mn = mean0[b * 16 + i];
#pragma unroll 1
    for (int s = 0; s < seg; ++s) {
        const float wv = wseg[(size_t)s * 4096 + b * 16 + i];
        const float c0 = (s == 0) ? m0s[0] : mps[0];
        const float c1 = (s == 0) ? m0s[1] : mps[1];
        const float c2 = (s == 0) ? m0s[2] : mps[2];
        const float c3 = (s == 0) ? m0s[3] : mps[3];
        float part = c0 * __shfl(mn, 4 * g + 0) + c1 * __shfl(mn, 4 * g + 1)
                   + c2 * __shfl(mn, 4 * g + 2) + c3 * __shfl(mn, 4 * g + 3);
        part += __shfl_xor(part, 16);
        part += __shfl_xor(part, 32);
        mn = part + wv;
    }

    // ---- interior (verified phC with direct-load gv) ----
    float mcs[16][4];
    if (seg == 0) {
#pragma unroll
        for (int j = 0; j < 16; ++j) {
            const float4 v = *(const float4*)(wsM + (size_t)j * 256 + i * 16 + 4 * g);
            mcs[j][0] = v.x; mcs[j][1] = v.y; mcs[j][2] = v.z; mcs[j][3] = v.w;
        }
    } else {
        const float4 v = *(const float4*)(wsM + (size_t)16 * 256 + i * 16 + 4 * g);
        mcs[0][0] = v.x; mcs[0][1] = v.y; mcs[0][2] = v.z; mcs[0][3] = v.w;
    }
    float kc[8], nbc[8];
    if (seg != 0) {
        const float4 k0 = *(const float4*)(wsK + (size_t)16 * 512 + i * 32 + 8 * g);
        const float4 k1 = *(const float4*)(wsK + (size_t)16 * 512 + i * 32 + 8 * g + 4);
        const float4 n0 = *(const float4*)(wsN + (size_t)16 * 128 + i * 8);
        const float4 n1 = *(const float4*)(wsN + (size_t)16 * 128 + i * 8 + 4);
        kc[0]=k0.x; kc[1]=k0.y; kc[2]=k0.z; kc[3]=k0.w;
        kc[4]=k1.x; kc[5]=k1.y; kc[6]=k1.z; kc[7]=k1.w;
        nbc[0]=n0.x; nbc[1]=n0.y; nbc[2]=n0.z; nbc[3]=n0.w;
        nbc[4]=n1.x; nbc[5]=n1.y; nbc[6]=n1.z; nbc[7]=n1.w;
    }

    const float* ab = a + (size_t)b * (TT * 32);
    const float* ub = u + (size_t)b * (TT * 8);
    float* ob = out + (size_t)b * 4096 + (size_t)(16 * seg) * 16;
#pragma unroll
    for (int j = 0; j < 16; ++j) {
        const int t = 16 * seg + j;
        float kr[8], nbr[8];
        if (seg == 0) {
            const float4 k0 = *(const float4*)(wsK + (size_t)j * 512 + i * 32 + 8 * g);
            const float4 k1 = *(const float4*)(wsK + (size_t)j * 512 + i * 32 + 8 * g + 4);
            const float4 n0 = *(const float4*)(wsN + (size_t)j * 128 + i * 8);
            const float4 n1 = *(const float4*)(wsN + (size_t)j * 128 + i * 8 + 4);
            kr[0]=k0.x; kr[1]=k0.y; kr[2]=k0.z; kr[3]=k0.w;
            kr[4]=k1.x; kr[5]=k1.y; kr[6]=k1.z; kr[7]=k1.w;
            nbr[0]=n0.x; nbr[1]=n0.y; nbr[2]=n0.z; nbr[3]=n0.w;
            nbr[4]=n1.x; nbr[5]=n1.y; nbr[6]=n1.z; nbr[7]=n1.w;
        } else {
#pragma unroll
            for (int k = 0; k < 8; ++k) { kr[k] = kc[k]; nbr[k] = nbc[k]; }
        }
        const float4 av0 = *(const float4*)(ab + t * 32 + 8 * g);
        const float4 av1 = *(const float4*)(ab + t * 32 + 8 * g + 4);
        const float4 uv0 = *(const float4*)(ub + t * 8);
        const float4 uv1 = *(const float4*)(ub + t * 8 + 4);
        float gvp = kr[0]*av0.x + kr[1]*av0.y + kr[2]*av0.z + kr[3]*av0.w
                  + kr[4]*av1.x + kr[5]*av1.y + kr[6]*av1.z + kr[7]*av1.w;
        float nbs = nbr[0]*uv0.x + nbr[1]*uv0.y + nbr[2]*uv0.z + nbr[3]*uv0.w
                  + nbr[4]*uv1.x + nbr[5]*uv1.y + nbr[6]*uv1.z + nbr[7]*uv1.w;
        gvp += (g == 3) ? nbs : 0.f;
        gvp += __shfl_xor(gvp, 16);
        gvp += __shfl_xor(gvp, 32);
        const float* mr = (seg == 0) ? mcs[j] : mcs[0];
        float part = mr[0] * __shfl(mn, 4*g+0) + mr[1] * __shfl(mn, 4*g+1)
                   + mr[2] * __shfl(mn, 4*g+2) + mr[3] * __shfl(mn, 4*g+3);
        part += __shfl_xor(part, 16);
        part += __shfl_xor(part, 32);
        mn = part + gvp;
        if (lane < 16) ob[j * 16 + i] = mn;
    }
}

// ---------------------------------------------------------------------------
// Fallback (verified R6/R8/R9, unchanged): serial mean pass if ws too small.
// ---------------------------------------------------------------------------
__global__ __launch_bounds__(64) void meanf_k(
    const float* __restrict__ mean0, const float* __restrict__ u,
    const float* __restrict__ a, const float* __restrict__ wsK,
    const float* __restrict__ wsM, const float* __restrict__ wsN,
    float* __restrict__ out)
{
    const int lane = threadIdx.x;
    const int b = blockIdx.x;
    const int i = lane & 15;
    const int g = lane >> 4;

    const float* ub = u + (size_t)b * TT * 8;
    const float* ab = a + (size_t)b * TT * 32;
    float* ob = out + (size_t)b * TT * 16;

    float mn = mean0[b * 16 + i];
    float Mc[16];
    {
        const float4* p = (const float4*)(wsM + i * 16);
        float4 x0 = p[0], x1 = p[1], x2 = p[2], x3 = p[3];
        Mc[0]=x0.x; Mc[1]=x0.y; Mc[2]=x0.z; Mc[3]=x0.w;
        Mc[4]=x1.x; Mc[5]=x1.y; Mc[6]=x1.z; Mc[7]=x1.w;
        Mc[8]=x2.x; Mc[9]=x2.y; Mc[10]=x2.z; Mc[11]=x2.w;
        Mc[12]=x3.x; Mc[13]=x3.y; Mc[14]=x3.z; Mc[15]=x3.w;
    }
    float gv;
    {
        float4 k0 = *(const float4*)(wsK + i * 32 + 8 * g);
        float4 k1 = *(const float4*)(wsK + i * 32 + 8 * g + 4);
        float4 n0 = *(const float4*)(wsN + i * 8);
        float4 n1 = *(const float4*)(wsN + i * 8 + 4);
        float u0 = ub[lane & 7];
        float a0 = ab[lane & 31];
        float part = k0.x * __shfl(a0, 8*g+0) + k0.y * __shfl(a0, 8*g+1)
                   + k0.z * __shfl(a0, 8*g+2) + k0.w * __shfl(a0, 8*g+3)
                   + k1.x * __shfl(a0, 8*g+4) + k1.y * __shfl(a0, 8*g+5)
                   + k1.z * __shfl(a0, 8*g+6) + k1.w * __shfl(a0, 8*g+7);
        float nbs = n0.x * __shfl(u0,0) + n0.y * __shfl(u0,1)
                  + n0.z * __shfl(u0,2) + n0.w * __shfl(u0,3)
                  + n1.x * __shfl(u0,4) + n1.y * __shfl(u0,5)
                  + n1.z * __shfl(u0,6) + n1.w * __shfl(u0,7);
        part += (g == 3) ? nbs : 0.f;
        part += __shfl_xor(part, 16);
        part += __shfl_xor(part, 32);
        gv = part;
    }
    float4 mA, mB, mC, mD, kp0, kp1, np0, np1;
    float upn, apn;
    {
        const float4* p = (const float4*)(wsM + 256 + i * 16);
        mA = p[0]; mB = p[1]; mC = p[2]; mD = p[3];
        kp0 = *(const float4*)(wsK + 512 + i * 32 + 8 * g);
        kp1 = *(const float4*)(wsK + 512 + i * 32 + 8 * g + 4);
        np0 = *(const float4*)(wsN + 128 + i * 8);
        np1 = *(const float4*)(wsN + 128 + i * 8 + 4);
        upn = ub[8 + (lane & 7)];
        apn = ab[32 + (lane & 31)];
    }

    for (int t = 0; t < TT; ++t) {
        const int t2 = (t + 2 < TT) ? t + 2 : TT - 1;
        const int s2 = (t2 < WARM) ? t2 : WARM;
        const float4* mp = (const float4*)(wsM + (size_t)s2 * 256 + i * 16);
        float4 l0 = mp[0], l1 = mp[1], l2 = mp[2], l3 = mp[3];
        float4 kl0 = *(const float4*)(wsK + (size_t)s2 * 512 + i * 32 + 8 * g);
        float4 kl1 = *(const float4*)(wsK + (size_t)s2 * 512 + i * 32 + 8 * g + 4);
        float4 nl0 = *(const float4*)(wsN + (size_t)s2 * 128 + i * 8);
        float4 nl1 = *(const float4*)(wsN + (size_t)s2 * 128 + i * 8 + 4);
        float ul = ub[t2 * 8 + (lane & 7)];
        float al = ab[t2 * 32 + (lane & 31)];

        float s0 = gv, s1 = 0.f, s2f = 0.f, s3 = 0.f;
#pragma unroll
        for (int q = 0; q < 16; q += 4) {
            s0  += Mc[q]     * __shfl(mn, q);
            s1  += Mc[q + 1] * __shfl(mn, q + 1);
            s2f += Mc[q + 2] * __shfl(mn, q + 2);
            s3  += Mc[q + 3] * __shfl(mn, q + 3);
        }
        mn = (s0 + s1) + (s2f + s3);
        if (lane < 16) ob[t * 16 + lane] = mn;

        float part = kp0.x * __shfl(apn, 8*g+0) + kp0.y * __shfl(apn, 8*g+1)
                   + kp0.z * __shfl(apn, 8*g+2) + kp0.w * __shfl(apn, 8*g+3)
                   + kp1.x * __shfl(apn, 8*g+4) + kp1.y * __shfl(apn, 8*g+5)
                   + kp1.z * __shfl(apn, 8*g+6) + kp1.w * __shfl(apn, 8*g+7);
        float nbs = np0.x * __shfl(upn,0) + np0.y * __shfl(upn,1)
                  + np0.z * __shfl(upn,2) + np0.w * __shfl(upn,3)
                  + np1.x * __shfl(upn,4) + np1.y * __shfl(upn,5)
                  + np1.z * __shfl(upn,6) + np1.w * __shfl(upn,7);
        part += (g == 3) ? nbs : 0.f;
        part += __shfl_xor(part, 16);
        part += __shfl_xor(part, 32);
        gv = part;

        Mc[0]=mA.x; Mc[1]=mA.y; Mc[2]=mA.z; Mc[3]=mA.w;
        Mc[4]=mB.x; Mc[5]=mB.y; Mc[6]=mB.z; Mc[7]=mB.w;
        Mc[8]=mC.x; Mc[9]=mC.y; Mc[10]=mC.z; Mc[11]=mC.w;
        Mc[12]=mD.x; Mc[13]=mD.y; Mc[14]=mD.z; Mc[15]=mD.w;
        mA = l0; mB = l1; mC = l2; mD = l3;
        kp0 = kl0; kp1 = kl1; np0 = nl0; np1 = nl1;
        upn = ul; apn = al;
    }
}

extern "C" void kernel_launch(void* const* d_in, const int* in_sizes, int n_in,
                              void* d_out, int out_size, void* d_ws, size_t ws_size,
                              hipStream_t stream) {
    const float* mean0 = nullptr; const float* cov0 = nullptr;
    const float* u = nullptr;     const float* a = nullptr;
    const float* Mm = nullptr;    const float* Nm = nullptr;
    const float* dv = nullptr;    const float* Bm = nullptr;
    const float* Cm = nullptr;    const float* nxp = nullptr;
    const float* nap = nullptr;
    for (int i = 0; i < n_in; ++i) {
        const float* p = (const float*)d_in[i];
        switch (in_sizes[i]) {
            case 256 * 16:        mean0 = p; break;
            case 256 * 256:       cov0 = p; break;
            case 256 * 256 * 8:   u = p; break;
            case 256 * 256 * 32:  a = p; break;
            case 256:             if (!Mm) Mm = p; else Nm = p; break;
            case 16:              if (!dv) dv = p; else nxp = p; break;
            case 128:             Bm = p; break;
            case 512:             Cm = p; break;
            case 32:              nap = p; break;
            default: break;
        }
    }
    float* ws   = (float*)d_ws;
    float* wsK  = ws + OFF_K;
    float* wsM  = ws + OFF_MC;
    float* wsN  = ws + OFF_NB;
    float* wsp  = ws + OFF_P0;
    float* wseg = ws + OFF_WSEG;

    chain_k<<<WARM + 1, 64, 0, stream>>>(Mm, Nm, dv, Bm, Cm, nxp, nap, cov0,
                                         wsK, wsM, wsN);
    if (ws_size >= NEED_WS_BYTES) {
        phA_k<<<16 * 256, 64, 0, stream>>>(u, a, wsK, wsM, wsN, wseg, wsp);
        phBC_k<<<16 * 256, 64, 0, stream>>>(mean0, u, a, wsK, wsM, wsN, wsp, wseg,
                                            (float*)d_out);
    } else {
        meanf_k<<<256, 64, 0, stream>>>(mean0, u, a, wsK, wsM, wsN, (float*)d_out);
    }
}

// Round 15
// 203.332 us; speedup vs baseline: 1.4090x; 1.4090x over previous
//
#include <hip/hip_runtime.h>
#include <math.h>

#define TT 256
#define WARM 16
// ws float offsets (chain outputs + scan intermediates only)
#define OFF_K    5632   // 17 x 512 -> 14336
#define OFF_MC   14336  // 17 x 256 -> 18688
#define OFF_NB   18688  // 17 x 128 -> 20864
#define OFF_P0   20864  // Mseg0 (256) -> 21120
#define OFF_PP   21120  // Mc16^16 (256) -> 21376
#define OFF_WSEG 21376  // 16 x 256 x 16 -> 86912
#define OFF_BND  86912  // 16 x 256 x 16 -> 152448
#define NEED_WS_BYTES ((size_t)152448 * 4)

__device__ __forceinline__ float softplus(float v) {
    return fmaxf(v, 0.0f) + log1pf(expf(-fabsf(v)));
}

// Shuffle-based Gauss-Jordan, [X|I] -> [I|X^-1] (verified R5-R13).
__device__ __forceinline__ void gj16(float (&aug)[8], const int i, const int gq) {
#pragma unroll
    for (int j = 0; j < 16; ++j) {
        float prow[8];
#pragma unroll
        for (int k = 0; k < 8; ++k) prow[k] = __shfl(aug[k], j + 16 * gq);
        const float pjj = __shfl(aug[j & 7], j + 16 * (j >> 3));
        const float cij = __shfl(aug[j & 7], i + 16 * (j >> 3));
        const float pivinv = 1.0f / pjj;
        const float f = cij * pivinv;
#pragma unroll
        for (int k = 0; k < 8; ++k)
            aug[k] = (i == j) ? prow[k] * pivinv : aug[k] - f * prow[k];
    }
}

// ---------------------------------------------------------------------------
// Fused chain kernel (verified R13, unchanged): 17 blocks x 64 threads.
// ---------------------------------------------------------------------------
__global__ __launch_bounds__(64) void chain_k(
    const float* __restrict__ Mm, const float* __restrict__ Nm,
    const float* __restrict__ dvec, const float* __restrict__ Bm,
    const float* __restrict__ Cm, const float* __restrict__ nx,
    const float* __restrict__ na, const float* __restrict__ cov0,
    float* __restrict__ wsK, float* __restrict__ wsM, float* __restrict__ wsN)
{
    __shared__ float qm[16][17], qn[16][17], T0s[16][17];
    __shared__ float sC[32][17], sW[16][33], sAm[16][17], sBm[16][9];
    __shared__ float sE[16][17], sF[16][17], sH[16][17], sScr[16][17];
    __shared__ float sCA[32][17], sCB[32][9], sP[16][17], sK[16][33];
    __shared__ float spv[16], d2[16], sNai[32], sNxi[16];
    const int lane = threadIdx.x;
    const int t = blockIdx.x;            // 0..16
    const int n = t + 1;                 // steps to apply
    const int i = lane & 15, gq = lane >> 4, h = gq & 1;

    for (int e = lane; e < 256; e += 64) { qm[e >> 4][e & 15] = Mm[e]; qn[e >> 4][e & 15] = Nm[e]; }
    for (int e = lane; e < 512; e += 64) sC[e >> 4][e & 15] = Cm[e];
    for (int e = lane; e < 128; e += 64) sBm[e >> 3][e & 7] = Bm[e];
    if (lane < 16) {
        float s = softplus(dvec[lane]);
        spv[lane] = sqrtf(s);
        d2[lane] = 1.0f / sqrtf(1.0f + s);
        sNxi[lane] = 1.0f / (softplus(nx[lane]) + 1e-4f);
    }
    if (lane < 32) sNai[lane] = 1.0f / (softplus(na[lane]) + 1e-4f);
    __syncthreads();

    // register MGS QR (verified R12/R13)
    {
        const int j0 = lane & 15;
        const int mi = lane >> 4;
        float (*Qs)[17] = (mi == 1) ? qn : qm;
        float col[16];
#pragma unroll
        for (int r = 0; r < 16; ++r) col[r] = Qs[r][j0];
        const int base = lane & 48;
#pragma unroll 1
        for (int j = 0; j < 16; ++j) {
            float qj[16];
#pragma unroll
            for (int r = 0; r < 16; ++r) qj[r] = __shfl(col[r], base + j);
            float nrm = 0.f;
#pragma unroll
            for (int r = 0; r < 16; ++r) nrm += qj[r] * qj[r];
            const float scal = 1.0f / sqrtf(nrm);
#pragma unroll
            for (int r = 0; r < 16; ++r) qj[r] *= scal;
            if (j0 == j) {
#pragma unroll
                for (int r = 0; r < 16; ++r) col[r] = qj[r];
            } else if (j0 > j) {
                float pr = 0.f;
#pragma unroll
                for (int r = 0; r < 16; ++r) pr += qj[r] * col[r];
#pragma unroll
                for (int r = 0; r < 16; ++r) col[r] -= pr * qj[r];
            }
        }
        __syncthreads();
        if (mi < 2) {
#pragma unroll
            for (int r = 0; r < 16; ++r) Qs[r][j0] = col[r];
        }
    }
    __syncthreads();

    // assembly (verified R13)
    for (int e = lane; e < 256; e += 64) {
        int ii = e >> 4, j = e & 15;
        float s = 0.f;
        for (int q = 0; q < 16; ++q) s += qm[ii][q] * d2[q] * qn[j][q];
        T0s[ii][j] = spv[ii] * s;
    }
    __syncthreads();
    for (int e = lane; e < 256; e += 64) {
        int ii = e >> 4, j = e & 15;
        float s = 0.f;
        for (int q = 0; q < 16; ++q) s += qn[ii][q] * T0s[q][j];
        sAm[ii][j] = s;
    }
    for (int e = lane; e < 512; e += 64) {
        int q = e >> 5, r = e & 31;
        sW[q][r] = sC[r][q] * sNai[r];
    }
    __syncthreads();
    for (int e = lane; e < 256; e += 64) {
        int ii = e >> 4, j = e & 15;
        float g = 0.f;
        for (int r = 0; r < 32; ++r) g += sC[r][ii] * sW[j][r];
        sF[ii][j] = g + ((ii == j) ? sNxi[ii] : 0.f);
        sE[ii][j] = sNxi[ii] * sAm[ii][j];
        float hsum = 0.f;
        for (int q = 0; q < 16; ++q) hsum += sAm[q][ii] * sNxi[q] * sAm[q][j];
        sH[ii][j] = hsum;
    }
    for (int e = lane; e < 512; e += 64) {
        int r = e >> 4, j = e & 15;
        float s = 0.f;
        for (int q = 0; q < 16; ++q) s += sC[r][q] * sAm[q][j];
        sCA[r][j] = s;
    }
    for (int e = lane; e < 256; e += 64) {
        int r = e >> 3, j = e & 7;
        float s = 0.f;
        for (int q = 0; q < 16; ++q) s += sC[r][q] * sBm[q][j];
        sCB[r][j] = s;
    }
    __syncthreads();

    float Erow[16], ETrow[16], Fr[8], Hr[8];
#pragma unroll
    for (int q = 0; q < 16; ++q) { Erow[q] = sE[i][q]; ETrow[q] = sE[q][i]; }
#pragma unroll
    for (int k = 0; k < 8; ++k) { Fr[k] = sF[i][8 * h + k]; Hr[k] = sH[i][8 * h + k]; }

    float aug[8];
#pragma unroll
    for (int k = 0; k < 8; ++k)
        aug[k] = (gq < 2) ? cov0[i * 16 + 8 * gq + k]
                          : ((8 * (gq - 2) + k == i) ? 1.f : 0.f);
    gj16(aug, i, gq);
    float L_r[8];
#pragma unroll
    for (int k = 0; k < 8; ++k) L_r[k] = __shfl(aug[k], i + 16 * (2 + h));

#pragma unroll 1
    for (int m = 0; m < 5; ++m) {
        if ((n >> m) & 1) {
#pragma unroll
            for (int k = 0; k < 8; ++k)
                aug[k] = (gq < 2) ? (L_r[k] + Hr[k]) : ((8 * (gq - 2) + k == i) ? 1.f : 0.f);
            gj16(aug, i, gq);
            float T_r[8];
#pragma unroll
            for (int k = 0; k < 8; ++k) T_r[k] = 0.f;
#pragma unroll
            for (int q = 0; q < 16; ++q) {
                const float eq = Erow[q];
#pragma unroll
                for (int k = 0; k < 8; ++k) T_r[k] += eq * __shfl(aug[k], q + 16 * (2 + h));
            }
            float Trow[16];
#pragma unroll
            for (int q = 0; q < 16; ++q) Trow[q] = __shfl(T_r[q & 7], i + 16 * (q >> 3));
#pragma unroll
            for (int k = 0; k < 8; ++k) L_r[k] = Fr[k];
#pragma unroll
            for (int q = 0; q < 16; ++q) {
                const float tq = Trow[q];
#pragma unroll
                for (int k = 0; k < 8; ++k) L_r[k] -= tq * __shfl(Erow[q], 8 * h + k);
            }
        }
        if (m < 4) {
#pragma unroll
            for (int k = 0; k < 8; ++k)
                aug[k] = (gq < 2) ? (Fr[k] + Hr[k]) : ((8 * (gq - 2) + k == i) ? 1.f : 0.f);
            gj16(aug, i, gq);
            float Z_r[8];
#pragma unroll
            for (int k = 0; k < 8; ++k) Z_r[k] = __shfl(aug[k], i + 16 * (2 + h));
            float T_r[8], T2_r[8];
#pragma unroll
            for (int k = 0; k < 8; ++k) { T_r[k] = 0.f; T2_r[k] = 0.f; }
#pragma unroll
            for (int q = 0; q < 16; ++q) {
                const float eq = Erow[q], etq = ETrow[q];
#pragma unroll
                for (int k = 0; k < 8; ++k) {
                    const float z = __shfl(Z_r[k], q + 16 * h);
                    T_r[k] += eq * z;
                    T2_r[k] += etq * z;
                }
            }
            float Trow[16], T2row[16];
#pragma unroll
            for (int q = 0; q < 16; ++q) {
                Trow[q] = __shfl(T_r[q & 7], i + 16 * (q >> 3));
                T2row[q] = __shfl(T2_r[q & 7], i + 16 * (q >> 3));
            }
            float F2r[8], H2r[8], E2r[8];
#pragma unroll
            for (int k = 0; k < 8; ++k) { F2r[k] = Fr[k]; H2r[k] = Hr[k]; E2r[k] = 0.f; }
#pragma unroll
            for (int q = 0; q < 16; ++q) {
                const float tq = Trow[q], t2q = T2row[q];
#pragma unroll
                for (int k = 0; k < 8; ++k) {
                    const float ecol = __shfl(Erow[q], 8 * h + k);
                    const float etcol = __shfl(ETrow[q], 8 * h + k);
                    F2r[k] -= tq * ecol;
                    H2r[k] -= t2q * etcol;
                    E2r[k] += tq * etcol;
                }
            }
            __syncthreads();
            if (lane < 32) {
#pragma unroll
                for (int k = 0; k < 8; ++k) sScr[i][8 * h + k] = E2r[k];
            }
            __syncthreads();
#pragma unroll
            for (int q = 0; q < 16; ++q) { Erow[q] = sScr[i][q]; ETrow[q] = sScr[q][i]; }
#pragma unroll
            for (int k = 0; k < 8; ++k) { Fr[k] = F2r[k]; Hr[k] = H2r[k]; }
        }
    }

    // epilogue (verified)
#pragma unroll
    for (int k = 0; k < 8; ++k)
        aug[k] = (gq < 2) ? L_r[k] : ((8 * (gq - 2) + k == i) ? 1.f : 0.f);
    gj16(aug, i, gq);
    float P_r[8];
#pragma unroll
    for (int k = 0; k < 8; ++k) P_r[k] = __shfl(aug[k], i + 16 * (2 + h));
    if (lane < 32) {
#pragma unroll
        for (int k = 0; k < 8; ++k) sP[i][8 * h + k] = P_r[k];
    }
    __syncthreads();
#pragma unroll
    for (int m = 0; m < 8; ++m) {
        const int e = lane + 64 * m, ii = e >> 5, rr = e & 31;
        float s = 0.f;
#pragma unroll
        for (int q = 0; q < 16; ++q) s += sP[ii][q] * sW[q][rr];
        sK[ii][rr] = s;
        wsK[(size_t)t * 512 + e] = s;
    }
    __syncthreads();
#pragma unroll
    for (int m = 0; m < 4; ++m) {
        const int e = lane + 64 * m, ii = e >> 4, jj = e & 15;
        float s = sAm[ii][jj];
#pragma unroll
        for (int r = 0; r < 32; ++r) s -= sK[ii][r] * sCA[r][jj];
        wsM[(size_t)t * 256 + e] = s;
    }
#pragma unroll
    for (int m = 0; m < 2; ++m) {
        const int e = lane + 64 * m, ii = e >> 3, jj = e & 7;
        float s = sBm[ii][jj];
#pragma unroll
        for (int r = 0; r < 32; ++r) s -= sK[ii][r] * sCB[r][jj];
        wsN[(size_t)t * 128 + e] = s;
    }
}

// ---------------------------------------------------------------------------
// Phase A (R15): R13 structure, broadcast-load gv (bit-identical values),
// seg!=0 prologue dedup. Blocks 0/256 emit P0/PP (verified emitters).
// ---------------------------------------------------------------------------
__global__ __launch_bounds__(64) void phA_k(
    const float* __restrict__ u, const float* __restrict__ a,
    const float* __restrict__ wsK, const float* __restrict__ wsM,
    const float* __restrict__ wsN, float* __restrict__ wseg,
    float* __restrict__ wsp)
{
    const int lane = threadIdx.x;
    const int i = lane & 15, g = lane >> 4;
    const int seg = blockIdx.x >> 8;
    const int b = blockIdx.x & 255;

    float mcs[16][4];
    if (seg == 0) {
#pragma unroll
        for (int j = 0; j < 16; ++j) {
            const float4 v = *(const float4*)(wsM + (size_t)j * 256 + i * 16 + 4 * g);
            mcs[j][0] = v.x; mcs[j][1] = v.y; mcs[j][2] = v.z; mcs[j][3] = v.w;
        }
    } else {
        const float4 v = *(const float4*)(wsM + (size_t)16 * 256 + i * 16 + 4 * g);
        mcs[0][0] = v.x; mcs[0][1] = v.y; mcs[0][2] = v.z; mcs[0][3] = v.w;
    }
    float kc[8], nbc[8];
    if (seg != 0) {
        const float4 k0 = *(const float4*)(wsK + (size_t)16 * 512 + i * 32 + 8 * g);
        const float4 k1 = *(const float4*)(wsK + (size_t)16 * 512 + i * 32 + 8 * g + 4);
        const float4 n0 = *(const float4*)(wsN + (size_t)16 * 128 + i * 8);
        const float4 n1 = *(const float4*)(wsN + (size_t)16 * 128 + i * 8 + 4);
        kc[0]=k0.x; kc[1]=k0.y; kc[2]=k0.z; kc[3]=k0.w;
        kc[4]=k1.x; kc[5]=k1.y; kc[6]=k1.z; kc[7]=k1.w;
        nbc[0]=n0.x; nbc[1]=n0.y; nbc[2]=n0.z; nbc[3]=n0.w;
        nbc[4]=n1.x; nbc[5]=n1.y; nbc[6]=n1.z; nbc[7]=n1.w;
    }

    const float* ab = a + (size_t)b * (TT * 32);
    const float* ub = u + (size_t)b * (TT * 8);

    float w = 0.f;
#pragma unroll
    for (int j = 0; j < 16; ++j) {
        const int t = 16 * seg + j;
        float kr[8], nbr[8];
        if (seg == 0) {
            const float4 k0 = *(const float4*)(wsK + (size_t)j * 512 + i * 32 + 8 * g);
            const float4 k1 = *(const float4*)(wsK + (size_t)j * 512 + i * 32 + 8 * g + 4);
            const float4 n0 = *(const float4*)(wsN + (size_t)j * 128 + i * 8);
            const float4 n1 = *(const float4*)(wsN + (size_t)j * 128 + i * 8 + 4);
            kr[0]=k0.x; kr[1]=k0.y; kr[2]=k0.z; kr[3]=k0.w;
            kr[4]=k1.x; kr[5]=k1.y; kr[6]=k1.z; kr[7]=k1.w;
            nbr[0]=n0.x; nbr[1]=n0.y; nbr[2]=n0.z; nbr[3]=n0.w;
            nbr[4]=n1.x; nbr[5]=n1.y; nbr[6]=n1.z; nbr[7]=n1.w;
        } else {
#pragma unroll
            for (int k = 0; k < 8; ++k) { kr[k] = kc[k]; nbr[k] = nbc[k]; }
        }
        const float4 av0 = *(const float4*)(ab + t * 32 + 8 * g);
        const float4 av1 = *(const float4*)(ab + t * 32 + 8 * g + 4);
        const float4 uv0 = *(const float4*)(ub + t * 8);
        const float4 uv1 = *(const float4*)(ub + t * 8 + 4);
        float gvp = kr[0]*av0.x + kr[1]*av0.y + kr[2]*av0.z + kr[3]*av0.w
                  + kr[4]*av1.x + kr[5]*av1.y + kr[6]*av1.z + kr[7]*av1.w;
        float nbs = nbr[0]*uv0.x + nbr[1]*uv0.y + nbr[2]*uv0.z + nbr[3]*uv0.w
                  + nbr[4]*uv1.x + nbr[5]*uv1.y + nbr[6]*uv1.z + nbr[7]*uv1.w;
        gvp += (g == 3) ? nbs : 0.f;
        gvp += __shfl_xor(gvp, 16);
        gvp += __shfl_xor(gvp, 32);
        const float* mr = (seg == 0) ? mcs[j] : mcs[0];
        float part = mr[0] * __shfl(w, 4*g+0) + mr[1] * __shfl(w, 4*g+1)
                   + mr[2] * __shfl(w, 4*g+2) + mr[3] * __shfl(w, 4*g+3);
        part += __shfl_xor(part, 16);
        part += __shfl_xor(part, 32);
        w = part + gvp;
    }
    if (lane < 16) wseg[(size_t)seg * 4096 + b * 16 + i] = w;

    if (blockIdx.x == 0) {          // P0 = Mc15 ... Mc0
        float pr[4];
#pragma unroll
        for (int k = 0; k < 4; ++k) pr[k] = (4 * g + k == i) ? 1.f : 0.f;
#pragma unroll
        for (int j = 0; j < 16; ++j) {
            float np[4] = {0.f, 0.f, 0.f, 0.f};
#pragma unroll
            for (int q = 0; q < 16; ++q) {
                const float mq = __shfl(mcs[j][q & 3], i + 16 * (q >> 2));
#pragma unroll
                for (int k = 0; k < 4; ++k) np[k] += mq * __shfl(pr[k], q + 16 * g);
            }
#pragma unroll
            for (int k = 0; k < 4; ++k) pr[k] = np[k];
        }
#pragma unroll
        for (int k = 0; k < 4; ++k) wsp[i * 16 + 4 * g + k] = pr[k];
    }
    if (blockIdx.x == 256) {        // PP = Mc16^16 (mcs[0] = Mc_16)
        float pr[4];
#pragma unroll
        for (int k = 0; k < 4; ++k) pr[k] = mcs[0][k];
#pragma unroll
        for (int r = 0; r < 4; ++r) {
            float np[4] = {0.f, 0.f, 0.f, 0.f};
#pragma unroll
            for (int q = 0; q < 16; ++q) {
                const float sq = __shfl(pr[q & 3], i + 16 * (q >> 2));
#pragma unroll
                for (int k = 0; k < 4; ++k) np[k] += sq * __shfl(pr[k], q + 16 * g);
            }
#pragma unroll
            for (int k = 0; k < 4; ++k) pr[k] = np[k];
        }
#pragma unroll
        for (int k = 0; k < 4; ++k) wsp[256 + i * 16 + 4 * g + k] = pr[k];
    }
}

// ---------------------------------------------------------------------------
// Phase B (verified R9-R13, restored): boundary recursion.
// ---------------------------------------------------------------------------
__global__ __launch_bounds__(64) void phB_k(
    const float* __restrict__ mean0, const float* __restrict__ wsp,
    const float* __restrict__ wseg, float* __restrict__ bnd)
{
    const int lane = threadIdx.x;
    const int i = lane & 15, g = lane >> 4;
    const int b = blockIdx.x;

    const float4 v0 = *(const float4*)(wsp + i * 16 + 4 * g);
    const float4 vp = *(const float4*)(wsp + 256 + i * 16 + 4 * g);
    const float m0s[4] = {v0.x, v0.y, v0.z, v0.w};
    const float mps[4] = {vp.x, vp.y, vp.z, vp.w};
    float wv[16];
#pragma unroll
    for (int s = 0; s < 16; ++s) wv[s] = wseg[(size_t)s * 4096 + b * 16 + i];

    float mn = mean0[b * 16 + i];
#pragma unroll
    for (int s = 0; s < 16; ++s) {
        if (lane < 16) bnd[(size_t)s * 4096 + b * 16 + i] = mn;
        const float c0 = (s == 0) ? m0s[0] : mps[0];
        const float c1 = (s == 0) ? m0s[1] : mps[1];
        const float c2 = (s == 0) ? m0s[2] : mps[2];
        const float c3 = (s == 0) ? m0s[3] : mps[3];
        float part = c0 * __shfl(mn, 4 * g + 0) + c1 * __shfl(mn, 4 * g + 1)
                   + c2 * __shfl(mn, 4 * g + 2) + c3 * __shfl(mn, 4 * g + 3);
        part += __shfl_xor(part, 16);
        part += __shfl_xor(part, 32);
        mn = part + wv[s];
    }
}

// ---------------------------------------------------------------------------
// Phase C (R15): R13 structure, broadcast-load gv, seg!=0 dedup.
// ---------------------------------------------------------------------------
__global__ __launch_bounds__(64) void phC_k(
    const float* __restrict__ u, const float* __restrict__ a,
    const float* __restrict__ wsK, const float* __restrict__ wsM,
    const float* __restrict__ wsN, const float* __restrict__ bnd,
    float* __restrict__ out)
{
    const int lane = threadIdx.x;
    const int i = lane & 15, g = lane >> 4;
    const int seg = blockIdx.x >> 8;
    const int b = blockIdx.x & 255;

    float mcs[16][4];
    if (seg == 0) {
#pragma unroll
        for (int j = 0; j < 16; ++j) {
            const float4 v = *(const float4*)(wsM + (size_t)j * 256 + i * 16 + 4 * g);
            mcs[j][0] = v.x; mcs[j][1] = v.y; mcs[j][2] = v.z; mcs[j][3] = v.w;
        }
    } else {
        const float4 v = *(const float4*)(wsM + (size_t)16 * 256 + i * 16 + 4 * g);
        mcs[0][0] = v.x; mcs[0][1] = v.y; mcs[0][2] = v.z; mcs[0][3] = v.w;
    }
    float kc[8], nbc[8];
    if (seg != 0) {
        const float4 k0 = *(const float4*)(wsK + (size_t)16 * 512 + i * 32 + 8 * g);
        const float4 k1 = *(const float4*)(wsK + (size_t)16 * 512 + i * 32 + 8 * g + 4);
        const float4 n0 = *(const float4*)(wsN + (size_t)16 * 128 + i * 8);
        const float4 n1 = *(const float4*)(wsN + (size_t)16 * 128 + i * 8 + 4);
        kc[0]=k0.x; kc[1]=k0.y; kc[2]=k0.z; kc[3]=k0.w;
        kc[4]=k1.x; kc[5]=k1.y; kc[6]=k1.z; kc[7]=k1.w;
        nbc[0]=n0.x; nbc[1]=n0.y; nbc[2]=n0.z; nbc[3]=n0.w;
        nbc[4]=n1.x; nbc[5]=n1.y; nbc[6]=n1.z; nbc[7]=n1.w;
    }

    const float* ab = a + (size_t)b * (TT * 32);
    const float* ub = u + (size_t)b * (TT * 8);
    float mn = bnd[(size_t)seg * 4096 + b * 16 + i];
    float* ob = out + (size_t)b * 4096 + (size_t)(16 * seg) * 16;
#pragma unroll
    for (int j = 0; j < 16; ++j) {
        const int t = 16 * seg + j;
        float kr[8], nbr[8];
        if (seg == 0) {
            const float4 k0 = *(const float4*)(wsK + (size_t)j * 512 + i * 32 + 8 * g);
            const float4 k1 = *(const float4*)(wsK + (size_t)j * 512 + i * 32 + 8 * g + 4);
            const float4 n0 = *(const float4*)(wsN + (size_t)j * 128 + i * 8);
            const float4 n1 = *(const float4*)(wsN + (size_t)j * 128 + i * 8 + 4);
            kr[0]=k0.x; kr[1]=k0.y; kr[2]=k0.z; kr[3]=k0.w;
            kr[4]=k1.x; kr[5]=k1.y; kr[6]=k1.z; kr[7]=k1.w;
            nbr[0]=n0.x; nbr[1]=n0.y; nbr[2]=n0.z; nbr[3]=n0.w;
            nbr[4]=n1.x; nbr[5]=n1.y; nbr[6]=n1.z; nbr[7]=n1.w;
        } else {
#pragma unroll
            for (int k = 0; k < 8; ++k) { kr[k] = kc[k]; nbr[k] = nbc[k]; }
        }
        const float4 av0 = *(const float4*)(ab + t * 32 + 8 * g);
        const float4 av1 = *(const float4*)(ab + t * 32 + 8 * g + 4);
        const float4 uv0 = *(const float4*)(ub + t * 8);
        const float4 uv1 = *(const float4*)(ub + t * 8 + 4);
        float gvp = kr[0]*av0.x + kr[1]*av0.y + kr[2]*av0.z + kr[3]*av0.w
                  + kr[4]*av1.x + kr[5]*av1.y + kr[6]*av1.z + kr[7]*av1.w;
        float nbs = nbr[0]*uv0.x + nbr[1]*uv0.y + nbr[2]*uv0.z + nbr[3]*uv0.w
                  + nbr[4]*uv1.x + nbr[5]*uv1.y + nbr[6]*uv1.z + nbr[7]*uv1.w;
        gvp += (g == 3) ? nbs : 0.f;
        gvp += __shfl_xor(gvp, 16);
        gvp += __shfl_xor(gvp, 32);
        const float* mr = (seg == 0) ? mcs[j] : mcs[0];
        float part = mr[0] * __shfl(mn, 4*g+0) + mr[1] * __shfl(mn, 4*g+1)
                   + mr[2] * __shfl(mn, 4*g+2) + mr[3] * __shfl(mn, 4*g+3);
        part += __shfl_xor(part, 16);
        part += __shfl_xor(part, 32);
        mn = part + gvp;
        if (lane < 16) ob[j * 16 + i] = mn;
    }
}

// ---------------------------------------------------------------------------
// Fallback (verified R6/R8/R9, unchanged): serial mean pass if ws too small.
// ---------------------------------------------------------------------------
__global__ __launch_bounds__(64) void meanf_k(
    const float* __restrict__ mean0, const float* __restrict__ u,
    const float* __restrict__ a, const float* __restrict__ wsK,
    const float* __restrict__ wsM, const float* __restrict__ wsN,
    float* __restrict__ out)
{
    const int lane = threadIdx.x;
    const int b = blockIdx.x;
    const int i = lane & 15;
    const int g = lane >> 4;

    const float* ub = u + (size_t)b * TT * 8;
    const float* ab = a + (size_t)b * TT * 32;
    float* ob = out + (size_t)b * TT * 16;

    float mn = mean0[b * 16 + i];
    float Mc[16];
    {
        const float4* p = (const float4*)(wsM + i * 16);
        float4 x0 = p[0], x1 = p[1], x2 = p[2], x3 = p[3];
        Mc[0]=x0.x; Mc[1]=x0.y; Mc[2]=x0.z; Mc[3]=x0.w;
        Mc[4]=x1.x; Mc[5]=x1.y; Mc[6]=x1.z; Mc[7]=x1.w;
        Mc[8]=x2.x; Mc[9]=x2.y; Mc[10]=x2.z; Mc[11]=x2.w;
        Mc[12]=x3.x; Mc[13]=x3.y; Mc[14]=x3.z; Mc[15]=x3.w;
    }
    float gv;
    {
        float4 k0 = *(const float4*)(wsK + i * 32 + 8 * g);
        float4 k1 = *(const float4*)(wsK + i * 32 + 8 * g + 4);
        float4 n0 = *(const float4*)(wsN + i * 8);
        float4 n1 = *(const float4*)(wsN + i * 8 + 4);
        float u0 = ub[lane & 7];
        float a0 = ab[lane & 31];
        float part = k0.x * __shfl(a0, 8*g+0) + k0.y * __shfl(a0, 8*g+1)
                   + k0.z * __shfl(a0, 8*g+2) + k0.w * __shfl(a0, 8*g+3)
                   + k1.x * __shfl(a0, 8*g+4) + k1.y * __shfl(a0, 8*g+5)
                   + k1.z * __shfl(a0, 8*g+6) + k1.w * __shfl(a0, 8*g+7);
        float nbs = n0.x * __shfl(u0,0) + n0.y * __shfl(u0,1)
                  + n0.z * __shfl(u0,2) + n0.w * __shfl(u0,3)
                  + n1.x * __shfl(u0,4) + n1.y * __shfl(u0,5)
                  + n1.z * __shfl(u0,6) + n1.w * __shfl(u0,7);
        part += (g == 3) ? nbs : 0.f;
        part += __shfl_xor(part, 16);
        part += __shfl_xor(part, 32);
        gv = part;
    }
    float4 mA, mB, mC, mD, kp0, kp1, np0, np1;
    float upn, apn;
    {
        const float4* p = (const float4*)(wsM + 256 + i * 16);
        mA = p[0]; mB = p[1]; mC = p[2]; mD = p[3];
        kp0 = *(const float4*)(wsK + 512 + i * 32 + 8 * g);
        kp1 = *(const float4*)(wsK + 512 + i * 32 + 8 * g + 4);
        np0 = *(const float4*)(wsN + 128 + i * 8);
        np1 = *(const float4*)(wsN + 128 + i * 8 + 4);
        upn = ub[8 + (lane & 7)];
        apn = ab[32 + (lane & 31)];
    }

    for (int t = 0; t < TT; ++t) {
        const int t2 = (t + 2 < TT) ? t + 2 : TT - 1;
        const int s2 = (t2 < WARM) ? t2 : WARM;
        const float4* mp = (const float4*)(wsM + (size_t)s2 * 256 + i * 16);
        float4 l0 = mp[0], l1 = mp[1], l2 = mp[2], l3 = mp[3];
        float4 kl0 = *(const float4*)(wsK + (size_t)s2 * 512 + i * 32 + 8 * g);
        float4 kl1 = *(const float4*)(wsK + (size_t)s2 * 512 + i * 32 + 8 * g + 4);
        float4 nl0 = *(const float4*)(wsN + (size_t)s2 * 128 + i * 8);
        float4 nl1 = *(const float4*)(wsN + (size_t)s2 * 128 + i * 8 + 4);
        float ul = ub[t2 * 8 + (lane & 7)];
        float al = ab[t2 * 32 + (lane & 31)];

        float s0 = gv, s1 = 0.f, s2f = 0.f, s3 = 0.f;
#pragma unroll
        for (int q = 0; q < 16; q += 4) {
            s0  += Mc[q]     * __shfl(mn, q);
            s1  += Mc[q + 1] * __shfl(mn, q + 1);
            s2f += Mc[q + 2] * __shfl(mn, q + 2);
            s3  += Mc[q + 3] * __shfl(mn, q + 3);
        }
        mn = (s0 + s1) + (s2f + s3);
        if (lane < 16) ob[t * 16 + lane] = mn;

        float part = kp0.x * __shfl(apn, 8*g+0) + kp0.y * __shfl(apn, 8*g+1)
                   + kp0.z * __shfl(apn, 8*g+2) + kp0.w * __shfl(apn, 8*g+3)
                   + kp1.x * __shfl(apn, 8*g+4) + kp1.y * __shfl(apn, 8*g+5)
                   + kp1.z * __shfl(apn, 8*g+6) + kp1.w * __shfl(apn, 8*g+7);
        float nbs = np0.x * __shfl(upn,0) + np0.y * __shfl(upn,1)
                  + np0.z * __shfl(upn,2) + np0.w * __shfl(upn,3)
                  + np1.x * __shfl(upn,4) + np1.y * __shfl(upn,5)
                  + np1.z * __shfl(upn,6) + np1.w * __shfl(upn,7);
        part += (g == 3) ? nbs : 0.f;
        part += __shfl_xor(part, 16);
        part += __shfl_xor(part, 32);
        gv = part;

        Mc[0]=mA.x; Mc[1]=mA.y; Mc[2]=mA.z; Mc[3]=mA.w;
        Mc[4]=mB.x; Mc[5]=mB.y; Mc[6]=mB.z; Mc[7]=mB.w;
        Mc[8]=mC.x; Mc[9]=mC.y; Mc[10]=mC.z; Mc[11]=mC.w;
        Mc[12]=mD.x; Mc[13]=mD.y; Mc[14]=mD.z; Mc[15]=mD.w;
        mA = l0; mB = l1; mC = l2; mD = l3;
        kp0 = kl0; kp1 = kl1; np0 = nl0; np1 = nl1;
        upn = ul; apn = al;
    }
}

extern "C" void kernel_launch(void* const* d_in, const int* in_sizes, int n_in,
                              void* d_out, int out_size, void* d_ws, size_t ws_size,
                              hipStream_t stream) {
    const float* mean0 = nullptr; const float* cov0 = nullptr;
    const float* u = nullptr;     const float* a = nullptr;
    const float* Mm = nullptr;    const float* Nm = nullptr;
    const float* dv = nullptr;    const float* Bm = nullptr;
    const float* Cm = nullptr;    const float* nxp = nullptr;
    const float* nap = nullptr;
    for (int i = 0; i < n_in; ++i) {
        const float* p = (const float*)d_in[i];
        switch (in_sizes[i]) {
            case 256 * 16:        mean0 = p; break;
            case 256 * 256:       cov0 = p; break;
            case 256 * 256 * 8:   u = p; break;
            case 256 * 256 * 32:  a = p; break;
            case 256:             if (!Mm) Mm = p; else Nm = p; break;
            case 16:              if (!dv) dv = p; else nxp = p; break;
            case 128:             Bm = p; break;
            case 512:             Cm = p; break;
            case 32:              nap = p; break;
            default: break;
        }
    }
    float* ws   = (float*)d_ws;
    float* wsK  = ws + OFF_K;
    float* wsM  = ws + OFF_MC;
    float* wsN  = ws + OFF_NB;
    float* wsp  = ws + OFF_P0;
    float* wseg = ws + OFF_WSEG;
    float* bnd  = ws + OFF_BND;

    chain_k<<<WARM + 1, 64, 0, stream>>>(Mm, Nm, dv, Bm, Cm, nxp, nap, cov0,
                                         wsK, wsM, wsN);
    if (ws_size >= NEED_WS_BYTES) {
        phA_k<<<16 * 256, 64, 0, stream>>>(u, a, wsK, wsM, wsN, wseg, wsp);
        phB_k<<<256, 64, 0, stream>>>(mean0, wsp, wseg, bnd);
        phC_k<<<16 * 256, 64, 0, stream>>>(u, a, wsK, wsM, wsN, bnd, (float*)d_out);
    } else {
        meanf_k<<<256, 64, 0, stream>>>(mean0, u, a, wsK, wsM, wsN, (float*)d_out);
    }
}